// Round 11
// baseline (258.744 us; speedup 1.0000x reference)
//
#include <hip/hip_runtime.h>
#include <math.h>

#define SK 7680          // 256 segments * 30 samples
#define NPTS 524288

// ---- workspace float offsets ----
#define WS_GQ_PART  0         // 32 partials x (96 sum + 96 sumsq)
#define WS_GK_PART  6144
#define WS_GQ_SCALE 12288
#define WS_GQ_SHIFT 12384
#define WS_GK_SCALE 12480
#define WS_GK_SHIFT 12576
#define WS_SEGX2    21888     // 256*96 raw view2 segment sums
#define WS_SEGG2    46464     // 256*96 head(view2) segment sums
#define WS_ANCHOR1  71040
#define WS_ANCHOR2  95616
#define WS_SAMPT    120192    // [7680][96] raw l2normed samples (row-major)
#define WS_SAMP2T   857472    // [7680][96] head l2normed samples (row-major)
#define WS_SROW     1594752   // [256][7680] sim2 matrix
#define WS_ZERO_CNT 71040     // zero partials + seg sums

typedef __attribute__((ext_vector_type(8))) short bf16x8;
typedef __attribute__((ext_vector_type(4))) float f32x4;

#define AS1 __attribute__((address_space(1)))
#define AS3 __attribute__((address_space(3)))

// async global->LDS, 16B per lane, LDS dst = wave-uniform base + lane*16
__device__ __forceinline__ void gl16(const float* g, char* l){
  __builtin_amdgcn_global_load_lds((const AS1 unsigned*)g, (AS3 unsigned*)l, 16, 0, 0);
}

// v_cvt_pk_bf16_f32 packing
__device__ __forceinline__ bf16x8 pack8(float4 a, float4 b){
  union { unsigned u[4]; bf16x8 v; } r;
  asm("v_cvt_pk_bf16_f32 %0, %1, %2" : "=v"(r.u[0]) : "v"(a.x), "v"(a.y));
  asm("v_cvt_pk_bf16_f32 %0, %1, %2" : "=v"(r.u[1]) : "v"(a.z), "v"(a.w));
  asm("v_cvt_pk_bf16_f32 %0, %1, %2" : "=v"(r.u[2]) : "v"(b.x), "v"(b.y));
  asm("v_cvt_pk_bf16_f32 %0, %1, %2" : "=v"(r.u[3]) : "v"(b.z), "v"(b.w));
  return r.v;
}
__device__ __forceinline__ bf16x8 pack8v(f32x4 a, f32x4 b){
  union { unsigned u[4]; bf16x8 v; } r;
  asm("v_cvt_pk_bf16_f32 %0, %1, %2" : "=v"(r.u[0]) : "v"(a[0]), "v"(a[1]));
  asm("v_cvt_pk_bf16_f32 %0, %1, %2" : "=v"(r.u[1]) : "v"(a[2]), "v"(a[3]));
  asm("v_cvt_pk_bf16_f32 %0, %1, %2" : "=v"(r.u[2]) : "v"(b[0]), "v"(b[1]));
  asm("v_cvt_pk_bf16_f32 %0, %1, %2" : "=v"(r.u[3]) : "v"(b[2]), "v"(b[3]));
  return r.v;
}
__device__ __forceinline__ float4 ld4(const float* p){
  return *reinterpret_cast<const float4*>(p);
}

// per-wave W fragments in registers: wf[i][kt], i = local ot index (global ot = oh*3+i)
__device__ __forceinline__ void build_wf(const float* __restrict__ W, bf16x8 wf[3][3],
                                         int oh, int lr, int g){
  #pragma unroll
  for (int i=0;i<3;i++){
    const float* wr = W + (unsigned)((oh*3+i)*16+lr)*96 + g*8;
    #pragma unroll
    for (int kt=0;kt<3;kt++)
      wf[i][kt] = pack8(ld4(wr + kt*32), ld4(wr + kt*32 + 4));
  }
}

// ---- stats over BOTH views (grid 4096, bid&1 ? v2 : v1): per-channel sum/sumsq of
// y = x @ W^T (bias cancels in BN). m97-style pipeline: global_load_lds staging,
// 2-deep LDS dbuf, counted vmcnt, raw s_barrier, asm ds_read A-frags.
__global__ __launch_bounds__(256) void stats_both(
    const float* __restrict__ V1, const float* __restrict__ V2,
    const float* __restrict__ Wk, const float* __restrict__ Wq,
    float* __restrict__ gpartK, float* __restrict__ gpartQ)
{
  __shared__ __align__(16) float xtile[2][3072];   // 2 x 12288 B
  __shared__ float red[96];
  const int tid = threadIdx.x;
  const int l = tid & 63, w = tid >> 6;
  const int g = l >> 4, lr = l & 15;
  const int rg = w & 1, oh = w >> 1;
  const int R = rg*16 + lr;

  const bool isv2 = (blockIdx.x & 1);
  const int  sub  = blockIdx.x >> 1;
  const float* X = isv2 ? V2 : V1;
  const float* W = isv2 ? Wq : Wk;

  bf16x8 wf[3][3];
  build_wf(W, wf, oh, lr, g);
  if (tid < 96) red[tid]=0.f;

  // stage-source precompute (swizzled chunk per slot)
  int so[3];
  #pragma unroll
  for (int i=0;i<3;i++){
    int s = i*256 + tid;
    int r = s/24, cp = s%24;
    int c = (cp & ~7) | ((cp & 7) ^ (r & 7));
    so[i] = r*96 + c*4;                       // float offset within 32x96 tile
  }
  const float* base = X + (long)sub*24576;    // 256 rows * 96
  char* lbase_c = (char*)&xtile[0][0] + w*1024;

  // A-frag swizzled read addresses (buffer 0; toggled ^12288 per iter)
  unsigned lb = (unsigned)(uintptr_t)&xtile[0][0];
  unsigned addrA = lb + R*384 + (unsigned)((( 2*g   ) ^ (R&7))*16);
  unsigned addrB = lb + R*384 + (unsigned)((((2*g)|1) ^ (R&7))*16);

#define STAGE(t, buf) {                                   \
    const float* tb = base + (t)*3072;                    \
    char* ld = lbase_c + (buf)*12288;                     \
    gl16(tb + so[0], ld);                                 \
    gl16(tb + so[1], ld + 4096);                          \
    gl16(tb + so[2], ld + 8192); }

  STAGE(0,0)
  STAGE(1,1)

  float sY[3]={0.f,0.f,0.f}, sY2[3]={0.f,0.f,0.f};

  #pragma unroll 1
  for (int it=0; it<8; ++it){
    if (it<7){ asm volatile("s_waitcnt vmcnt(3)" ::: "memory"); }
    else     { asm volatile("s_waitcnt vmcnt(0)" ::: "memory"); }
    __builtin_amdgcn_s_barrier();
    f32x4 xA0,xA1,xA2,xB0,xB1,xB2;
    asm volatile(
      "ds_read_b128 %0, %6\n\t"
      "ds_read_b128 %1, %6 offset:128\n\t"
      "ds_read_b128 %2, %6 offset:256\n\t"
      "ds_read_b128 %3, %7\n\t"
      "ds_read_b128 %4, %7 offset:128\n\t"
      "ds_read_b128 %5, %7 offset:256\n\t"
      "s_waitcnt lgkmcnt(0)"
      : "=&v"(xA0),"=&v"(xA1),"=&v"(xA2),"=&v"(xB0),"=&v"(xB1),"=&v"(xB2)
      : "v"(addrA), "v"(addrB) : "memory");
    __builtin_amdgcn_sched_barrier(0);
    __builtin_amdgcn_s_barrier();
    if (it<6) STAGE(it+2, it&1)
    bf16x8 a0 = pack8v(xA0,xB0), a1 = pack8v(xA1,xB1), a2 = pack8v(xA2,xB2);
    #pragma unroll
    for (int i=0;i<3;i++){
      f32x4 acc = {0.f,0.f,0.f,0.f};
      acc = __builtin_amdgcn_mfma_f32_16x16x32_bf16(a0, wf[i][0], acc, 0,0,0);
      acc = __builtin_amdgcn_mfma_f32_16x16x32_bf16(a1, wf[i][1], acc, 0,0,0);
      acc = __builtin_amdgcn_mfma_f32_16x16x32_bf16(a2, wf[i][2], acc, 0,0,0);
      sY[i]  += acc[0]+acc[1]+acc[2]+acc[3];
      sY2[i]  = fmaf(acc[0],acc[0],fmaf(acc[1],acc[1],
                fmaf(acc[2],acc[2],fmaf(acc[3],acc[3],sY2[i]))));
    }
    addrA ^= 12288u; addrB ^= 12288u;
  }
#undef STAGE

  __shared__ float red2[96];
  if (tid < 96) red2[tid]=0.f;
  __syncthreads();
  #pragma unroll
  for (int i=0;i<3;i++){
    float s = sY[i], s2 = sY2[i];
    s  += __shfl_xor(s,16);  s  += __shfl_xor(s,32);
    s2 += __shfl_xor(s2,16); s2 += __shfl_xor(s2,32);
    if (g==0){
      atomicAdd(&red[(oh*3+i)*16+lr],  s);
      atomicAdd(&red2[(oh*3+i)*16+lr], s2);
    }
  }
  __syncthreads();
  if (tid<96){
    float* dst = (isv2 ? gpartQ : gpartK) + (sub & 31)*192;
    atomicAdd(dst+tid,    red[tid]);
    atomicAdd(dst+96+tid, red2[tid]);
  }
}

// ---- apply pass (view2 only, grid 2048): relu(BN(y)) per-segment sums (SEGG2)
// + raw-x per-segment colsums (SEGX2). Same pipeline; colsums via LDS re-read.
__global__ __launch_bounds__(256) void head_apply_mfma(
    const float* __restrict__ X, const float* __restrict__ W,
    const float* __restrict__ scale, const float* __restrict__ shift,
    float* __restrict__ gsegRaw, float* __restrict__ gsegBN)
{
  __shared__ __align__(16) float xtile[2][3072];
  __shared__ float red[96];
  __shared__ float rsg[96];
  const int tid = threadIdx.x;
  const int l = tid & 63, w = tid >> 6;
  const int g = l >> 4, lr = l & 15;
  const int rg = w & 1, oh = w >> 1;
  const int R = rg*16 + lr;

  bf16x8 wf[3][3];
  build_wf(W, wf, oh, lr, g);
  if (tid < 96){ red[tid]=0.f; rsg[tid]=0.f; }

  float sc[3], sh[3];
  #pragma unroll
  for (int i=0;i<3;i++){
    sc[i]=scale[(oh*3+i)*16+lr]; sh[i]=shift[(oh*3+i)*16+lr];
  }

  int so[3], ck[3];
  #pragma unroll
  for (int i=0;i<3;i++){
    int s = i*256 + tid;
    int r = s/24, cp = s%24;
    int c = (cp & ~7) | ((cp & 7) ^ (r & 7));
    so[i] = r*96 + c*4;
    ck[i] = c;                               // chunk id held by this LDS slot
  }
  const float* base = X + (long)blockIdx.x*24576;
  char* lbase_c = (char*)&xtile[0][0] + w*1024;

  unsigned lb = (unsigned)(uintptr_t)&xtile[0][0];
  unsigned addrA = lb + R*384 + (unsigned)((( 2*g   ) ^ (R&7))*16);
  unsigned addrB = lb + R*384 + (unsigned)((((2*g)|1) ^ (R&7))*16);
  unsigned addrC = lb + tid*16;

#define STAGE(t, buf) {                                   \
    const float* tb = base + (t)*3072;                    \
    char* ld = lbase_c + (buf)*12288;                     \
    gl16(tb + so[0], ld);                                 \
    gl16(tb + so[1], ld + 4096);                          \
    gl16(tb + so[2], ld + 8192); }

  STAGE(0,0)
  STAGE(1,1)

  float zs[3]={0.f,0.f,0.f};
  f32x4 cs0={0.f,0.f,0.f,0.f}, cs1={0.f,0.f,0.f,0.f}, cs2={0.f,0.f,0.f,0.f};

  #pragma unroll 1
  for (int it=0; it<8; ++it){
    if (it<7){ asm volatile("s_waitcnt vmcnt(3)" ::: "memory"); }
    else     { asm volatile("s_waitcnt vmcnt(0)" ::: "memory"); }
    __builtin_amdgcn_s_barrier();
    f32x4 xA0,xA1,xA2,xB0,xB1,xB2,xC0,xC1,xC2;
    asm volatile(
      "ds_read_b128 %0, %9\n\t"
      "ds_read_b128 %1, %9 offset:128\n\t"
      "ds_read_b128 %2, %9 offset:256\n\t"
      "ds_read_b128 %3, %10\n\t"
      "ds_read_b128 %4, %10 offset:128\n\t"
      "ds_read_b128 %5, %10 offset:256\n\t"
      "ds_read_b128 %6, %11\n\t"
      "ds_read_b128 %7, %11 offset:4096\n\t"
      "ds_read_b128 %8, %11 offset:8192\n\t"
      "s_waitcnt lgkmcnt(0)"
      : "=&v"(xA0),"=&v"(xA1),"=&v"(xA2),"=&v"(xB0),"=&v"(xB1),"=&v"(xB2),
        "=&v"(xC0),"=&v"(xC1),"=&v"(xC2)
      : "v"(addrA), "v"(addrB), "v"(addrC) : "memory");
    __builtin_amdgcn_sched_barrier(0);
    __builtin_amdgcn_s_barrier();
    if (it<6) STAGE(it+2, it&1)
    cs0[0]+=xC0[0]; cs0[1]+=xC0[1]; cs0[2]+=xC0[2]; cs0[3]+=xC0[3];
    cs1[0]+=xC1[0]; cs1[1]+=xC1[1]; cs1[2]+=xC1[2]; cs1[3]+=xC1[3];
    cs2[0]+=xC2[0]; cs2[1]+=xC2[1]; cs2[2]+=xC2[2]; cs2[3]+=xC2[3];
    bf16x8 a0 = pack8v(xA0,xB0), a1 = pack8v(xA1,xB1), a2 = pack8v(xA2,xB2);
    #pragma unroll
    for (int i=0;i<3;i++){
      f32x4 acc = {0.f,0.f,0.f,0.f};
      acc = __builtin_amdgcn_mfma_f32_16x16x32_bf16(a0, wf[i][0], acc, 0,0,0);
      acc = __builtin_amdgcn_mfma_f32_16x16x32_bf16(a1, wf[i][1], acc, 0,0,0);
      acc = __builtin_amdgcn_mfma_f32_16x16x32_bf16(a2, wf[i][2], acc, 0,0,0);
      zs[i] += fmaxf(fmaf(acc[0],sc[i],sh[i]),0.f)
             + fmaxf(fmaf(acc[1],sc[i],sh[i]),0.f)
             + fmaxf(fmaf(acc[2],sc[i],sh[i]),0.f)
             + fmaxf(fmaf(acc[3],sc[i],sh[i]),0.f);
    }
    addrA ^= 12288u; addrB ^= 12288u; addrC ^= 12288u;
  }
#undef STAGE

  // raw colsums -> rsg
  #pragma unroll
  for (int k=0;k<4;k++) atomicAdd(&rsg[ck[0]*4+k], cs0[k]);
  #pragma unroll
  for (int k=0;k<4;k++) atomicAdd(&rsg[ck[1]*4+k], cs1[k]);
  #pragma unroll
  for (int k=0;k<4;k++) atomicAdd(&rsg[ck[2]*4+k], cs2[k]);
  // BN-relu colsums -> red
  #pragma unroll
  for (int i=0;i<3;i++){
    float s = zs[i];
    s += __shfl_xor(s,16); s += __shfl_xor(s,32);
    if (g==0) atomicAdd(&red[(oh*3+i)*16+lr], s);
  }
  __syncthreads();
  if (tid<96){
    atomicAdd(gsegRaw + (blockIdx.x>>3)*96 + tid, rsg[tid]);
    atomicAdd(gsegBN  + (blockIdx.x>>3)*96 + tid, red[tid]);
  }
}

// BN scale/shift from 32 partial sums (training-mode batch stats, biased var)
__global__ void bn_params_kernel(const float* __restrict__ gq_gamma, const float* __restrict__ gq_beta,
                                 const float* __restrict__ gk_gamma, const float* __restrict__ gk_beta,
                                 float* __restrict__ ws)
{
  const int t = threadIdx.x;
  const float invN = 1.0f/(float)NPTS;
  if (t < 96){
    float s=0.f, s2=0.f;
    #pragma unroll 4
    for (int p=0;p<32;p++){
      s  += ws[WS_GQ_PART + p*192 + t];
      s2 += ws[WS_GQ_PART + p*192 + 96 + t];
    }
    float mu  = s*invN;
    float var = s2*invN - mu*mu;
    float sc  = gq_gamma[t]*rsqrtf(var + 1e-5f);
    ws[WS_GQ_SCALE+t] = sc;
    ws[WS_GQ_SHIFT+t] = gq_beta[t] - mu*sc;
  } else if (t < 192){
    int c = t-96;
    float s=0.f, s2=0.f;
    #pragma unroll 4
    for (int p=0;p<32;p++){
      s  += ws[WS_GK_PART + p*192 + c];
      s2 += ws[WS_GK_PART + p*192 + 96 + c];
    }
    float mu  = s*invN;
    float var = s2*invN - mu*mu;
    float sc  = gk_gamma[c]*rsqrtf(var + 1e-5f);
    ws[WS_GK_SCALE+c] = sc;
    ws[WS_GK_SHIFT+c] = gk_beta[c] - mu*sc;
  }
}

// both anchors in one launch
__global__ __launch_bounds__(128) void anchor2x_kernel(
    const float* __restrict__ seg1, float* __restrict__ dst1,
    const float* __restrict__ seg2, float* __restrict__ dst2)
{
  __shared__ float red[128];
  const int t = threadIdx.x, s = blockIdx.x & 255;
  const float* segsum = (blockIdx.x < 256) ? seg1 : seg2;
  float* dst          = (blockIdx.x < 256) ? dst1 : dst2;
  float m = 0.f;
  if (t<96) m = segsum[s*96+t] * (1.0f/2048.0f);
  red[t] = m*m;
  __syncthreads();
  for (int off=64; off>0; off>>=1){
    if (t<off) red[t]+=red[t+off];
    __syncthreads();
  }
  float inv = 1.0f/(sqrtf(red[0]) + 1e-7f);
  if (t<96) dst[s*96+t] = m*inv;
}

// ---- fp32 96x96 tile GEMM helpers (used only by samples_kernel) ----
__device__ __forceinline__ void fma_row(float4& acc, const float4 x,
    const float4 w0, const float4 w1, const float4 w2, const float4 w3){
  acc.x = fmaf(x.x,w0.x, fmaf(x.y,w1.x, fmaf(x.z,w2.x, fmaf(x.w,w3.x, acc.x))));
  acc.y = fmaf(x.x,w0.y, fmaf(x.y,w1.y, fmaf(x.z,w2.y, fmaf(x.w,w3.y, acc.y))));
  acc.z = fmaf(x.x,w0.z, fmaf(x.y,w1.z, fmaf(x.z,w2.z, fmaf(x.w,w3.z, acc.z))));
  acc.w = fmaf(x.x,w0.w, fmaf(x.y,w1.w, fmaf(x.z,w2.w, fmaf(x.w,w3.w, acc.w))));
}
__device__ __forceinline__ void load_W(const float* __restrict__ W, float* Ws, int tid){
  #pragma unroll
  for (int i=0;i<12;i++){
    int f = i*768 + tid*4;
    int oc = f/96, k = f%96;
    float4 w4 = *reinterpret_cast<const float4*>(W + f);
    Ws[(k+0)*100+oc]=w4.x; Ws[(k+1)*100+oc]=w4.y;
    Ws[(k+2)*100+oc]=w4.z; Ws[(k+3)*100+oc]=w4.w;
  }
}
__device__ __forceinline__ void gemm_tile(const float* Xs, const float* Ws,
    int ocg, int rowg, int r0, float4 acc[4]){
  const float4* Xs4 = reinterpret_cast<const float4*>(Xs);
  const float4* Ws4 = reinterpret_cast<const float4*>(Ws);
  acc[0]=acc[1]=acc[2]=acc[3]=make_float4(0.f,0.f,0.f,0.f);
  #pragma unroll 4
  for (int k4=0;k4<24;k4++){
    float4 w0 = Ws4[(k4*4+0)*25 + ocg];
    float4 w1 = Ws4[(k4*4+1)*25 + ocg];
    float4 w2 = Ws4[(k4*4+2)*25 + ocg];
    float4 w3 = Ws4[(k4*4+3)*25 + ocg];
    #pragma unroll
    for (int jj=0;jj<4;jj++){
      float4 xv = Xs4[(r0+jj)*25 + (k4 ^ rowg)];
      fma_row(acc[jj], xv, w0, w1, w2, w3);
    }
  }
}

// gather 32 sampled view1 rows -> raw l2norm + gk-head l2norm, stored ROW-MAJOR [7680][96]
__global__ __launch_bounds__(192) void samples_kernel(
    const float* __restrict__ V1, const float* __restrict__ W,
    const float* __restrict__ scale, const float* __restrict__ shift,
    const int* __restrict__ idxs,
    float* __restrict__ sampT, float* __restrict__ samp2T)
{
  __shared__ __align__(16) float Ws[9600];
  __shared__ __align__(16) float Xs[3200];
  __shared__ __align__(16) float Gs[3200];
  __shared__ float invr[32], invh[32];
  const int tid = threadIdx.x;
  const int ocg = tid % 24, rowg = tid / 24;
  const int oc0 = ocg*4,  r0  = rowg*4;
  load_W(W, Ws, tid);
  const int base = blockIdx.x * 32;
  #pragma unroll
  for (int i=0;i<4;i++){
    int f = i*768 + tid*4;
    int row = f/96, col = f%96;
    int g = idxs[base+row];
    float4 v = *reinterpret_cast<const float4*>(V1 + g*96 + col);
    *reinterpret_cast<float4*>(Xs + row*100 + (col ^ ((row>>2)<<2))) = v;
  }
  __syncthreads();
  if (tid<32){
    float s=0.f;
    #pragma unroll
    for (int k=0;k<96;k++){ float v=Xs[tid*100+(k^((tid>>2)<<2))]; s=fmaf(v,v,s); }
    invr[tid]=1.0f/(sqrtf(s)+1e-7f);
  }
  __syncthreads();
  {
    int rr=tid&31, kg=tid>>5;
    float inv=invr[rr];
    #pragma unroll
    for (int kk=0;kk<16;kk++){
      int k=kg*16+kk;
      sampT[(long)(base+rr)*96 + k] = Xs[rr*100 + (k ^ ((rr>>2)<<2))]*inv;
    }
  }
  float4 acc[4];
  gemm_tile(Xs, Ws, ocg, rowg, r0, acc);
  float4 sc = make_float4(scale[oc0],scale[oc0+1],scale[oc0+2],scale[oc0+3]);
  float4 sh = make_float4(shift[oc0],shift[oc0+1],shift[oc0+2],shift[oc0+3]);
  #pragma unroll
  for (int jj=0;jj<4;jj++){
    int rr=r0+jj;
    float4 g;
    g.x=fmaxf(fmaf(acc[jj].x,sc.x,sh.x),0.f);
    g.y=fmaxf(fmaf(acc[jj].y,sc.y,sh.y),0.f);
    g.z=fmaxf(fmaf(acc[jj].z,sc.z,sh.z),0.f);
    g.w=fmaxf(fmaf(acc[jj].w,sc.w,sh.w),0.f);
    *reinterpret_cast<float4*>(Gs + rr*100 + (oc0 ^ ((rr>>2)<<2))) = g;
  }
  __syncthreads();
  if (tid<32){
    float s=0.f;
    #pragma unroll
    for (int k=0;k<96;k++){ float v=Gs[tid*100+(k^((tid>>2)<<2))]; s=fmaf(v,v,s); }
    invh[tid]=1.0f/(sqrtf(s)+1e-7f);
  }
  __syncthreads();
  {
    int rr=tid&31, kg=tid>>5;
    float inv=invh[rr];
    #pragma unroll
    for (int kk=0;kk<16;kk++){
      int k=kg*16+kk;
      samp2T[(long)(base+rr)*96 + k] = Gs[rr*100 + (k ^ ((rr>>2)<<2))]*inv;
    }
  }
}

// ---- sim2 = anchor2 @ samples2^T via MFMA: grid (30 col-tiles, 16 row-tiles) ----
__global__ __launch_bounds__(256) void sim2_mfma(
    const float* __restrict__ anchor2, const float* __restrict__ samp2,  // samp2 [7680][96]
    float* __restrict__ srowG)
{
  const int tid = threadIdx.x;
  const int l = tid & 63, w = tid >> 6;
  const int g = l >> 4, lr = l & 15;
  const int rowbase = blockIdx.y * 16;
  const int colbase = blockIdx.x * 256 + w * 64;

  bf16x8 af[3];
  const float* ar = anchor2 + (rowbase + lr)*96 + g*8;
  #pragma unroll
  for (int kt=0; kt<3; ++kt)
    af[kt] = pack8(ld4(ar + kt*32), ld4(ar + kt*32 + 4));

  #pragma unroll
  for (int sub=0; sub<4; ++sub){
    const float* br = samp2 + (long)(colbase + sub*16 + lr)*96 + g*8;
    float4 b00 = ld4(br);    float4 b01 = ld4(br+4);
    float4 b10 = ld4(br+32); float4 b11 = ld4(br+36);
    float4 b20 = ld4(br+64); float4 b21 = ld4(br+68);
    f32x4 acc = {0.f,0.f,0.f,0.f};
    acc = __builtin_amdgcn_mfma_f32_16x16x32_bf16(af[0], pack8(b00,b01), acc, 0,0,0);
    acc = __builtin_amdgcn_mfma_f32_16x16x32_bf16(af[1], pack8(b10,b11), acc, 0,0,0);
    acc = __builtin_amdgcn_mfma_f32_16x16x32_bf16(af[2], pack8(b20,b21), acc, 0,0,0);
    const int col  = colbase + sub*16 + lr;
    const int row0 = rowbase + g*4;
    #pragma unroll
    for (int i=0;i<4;i++)
      srowG[(long)(row0+i)*SK + col] = acc[i];
  }
}

// ---- fused Lcon1 + Lcon2: blocks 0..255 lcon2, 256..511 lcon1 (wave 0 only)
__global__ __launch_bounds__(256) void lcon12_kernel(
    const float* __restrict__ anchor1, const float* __restrict__ sampT,
    const float* __restrict__ srowG, const int* __restrict__ bg,
    float* __restrict__ out)
{
  const int tid = threadIdx.x;
  if (blockIdx.x >= 256){
    __shared__ float a[96];
    const int r = blockIdx.x - 256;
    if (tid < 64){
      for (int i=tid;i<96;i+=64) a[i]=anchor1[r*96+i];
      int c = 0;
      if (tid<30) c = r*30+tid;
      else if (tid<60){
        int j = tid-30;
        int p = (int)((double)j * 7649.0 / 29.0);   // linspace(0, M-1, 30).astype(int32)
        c = (p < r*30) ? p : p+30;                  // skip own block
      }
      float s=0.f;
      if (tid<60){
        const float* sr = sampT + (long)c*96;
        #pragma unroll
        for (int k4=0;k4<24;k4++){
          float4 v = *reinterpret_cast<const float4*>(sr + k4*4);
          s = fmaf(a[k4*4+0],v.x, fmaf(a[k4*4+1],v.y,
              fmaf(a[k4*4+2],v.z, fmaf(a[k4*4+3],v.w, s))));
        }
      }
      float logit = 2.0f*s;                          // /T, T=0.5
      float se = (tid<60) ? expf(logit) : 0.f;
      float sp = (tid<30) ? logit : 0.f;
      #pragma unroll
      for (int off=32; off; off>>=1){ se += __shfl_xor(se,off); sp += __shfl_xor(sp,off); }
      if (tid==0){
        float row = sp*(1.0f/30.0f) - logf(se);
        atomicAdd(out, -row*(1.0f/256.0f));
      }
    }
    return;
  }
  __shared__ float wvv[4];
  __shared__ int   wcc[4];
  __shared__ int   winc_s;
  __shared__ int   sel[30];
  const int r = blockIdx.x;
  const int lane = tid & 63, wid = tid >> 6;
  const float* __restrict__ rowp = srowG + (long)r*SK;
  float val[30];
  #pragma unroll
  for (int j=0;j<30;j++) val[j] = rowp[(j<<8) + tid];
  unsigned mask=0; float possum=0.f;
  for (int it=0; it<30; ++it){
    float bv = -3.0e38f; int bc = 1<<30;
    #pragma unroll
    for (int j=0;j<30;j++){
      if (!((mask>>j)&1u)){
        float v = val[j]; int c = tid + (j<<8);
        if (v > bv || (v == bv && c < bc)){ bv=v; bc=c; }
      }
    }
    #pragma unroll
    for (int off=32; off; off>>=1){
      float ov = __shfl_xor(bv, off); int ocx = __shfl_xor(bc, off);
      if (ov > bv || (ov == bv && ocx < bc)){ bv=ov; bc=ocx; }
    }
    if (lane==0){ wvv[wid]=bv; wcc[wid]=bc; }
    __syncthreads();
    if (tid==0){
      float v=wvv[0]; int c=wcc[0];
      #pragma unroll
      for (int w2=1;w2<4;w2++){
        if (wvv[w2]>v || (wvv[w2]==v && wcc[w2]<c)){ v=wvv[w2]; c=wcc[w2]; }
      }
      winc_s=c; sel[it]=c; possum += v;
    }
    __syncthreads();
    int c = winc_s;
    if ((c & 255) == tid) mask |= 1u << (c >> 8);
  }
  const int bgr = bg[r];
  float se=0.f;
  #pragma unroll
  for (int j=0;j<30;j++){
    int c = tid + (j<<8);
    int seg = c/30;
    int bgc = bg[seg];
    bool nf = ((bgr!=0) ? (bgc==0) : (bgc!=0)) && (seg != r);
    if (nf) se += expf(2.0f*val[j]);
  }
  #pragma unroll
  for (int off=32; off; off>>=1) se += __shfl_xor(se, off);
  if (lane==0) wvv[wid]=se;
  __syncthreads();
  float ex=0.f;
  if (tid<30){
    int c = sel[tid]; int seg=c/30; int bgc=bg[seg];
    bool nf = ((bgr!=0) ? (bgc==0) : (bgc!=0)) && (seg != r);
    if (!nf) ex = expf(2.0f*rowp[c]);        // positive not already in denom via neg
  }
  if (wid==0){
    #pragma unroll
    for (int off=32; off; off>>=1) ex += __shfl_xor(ex, off);
  }
  if (tid==0){
    float lse = logf(wvv[0]+wvv[1]+wvv[2]+wvv[3] + ex);
    float row = possum*(2.0f/30.0f) - lse;
    atomicAdd(out, -row*(1.0f/256.0f));
  }
}

extern "C" void kernel_launch(void* const* d_in, const int* in_sizes, int n_in,
                              void* d_out, int out_size, void* d_ws, size_t ws_size,
                              hipStream_t stream) {
  (void)in_sizes; (void)n_in; (void)out_size; (void)ws_size;
  const float* v1       = (const float*)d_in[0];
  const float* v2       = (const float*)d_in[1];
  const float* gq_w     = (const float*)d_in[2];
  const float* gq_gamma = (const float*)d_in[4];
  const float* gq_beta  = (const float*)d_in[5];
  const float* gk_w     = (const float*)d_in[6];
  const float* gk_gamma = (const float*)d_in[8];
  const float* gk_beta  = (const float*)d_in[9];
  const int*   idxs     = (const int*)d_in[12];
  const int*   bg       = (const int*)d_in[13];
  float* ws  = (float*)d_ws;
  float* out = (float*)d_out;

  hipMemsetAsync(ws, 0, (size_t)WS_ZERO_CNT*sizeof(float), stream);
  hipMemsetAsync(out, 0, sizeof(float), stream);

  stats_both<<<4096,256,0,stream>>>(v1, v2, gk_w, gq_w, ws+WS_GK_PART, ws+WS_GQ_PART);
  bn_params_kernel<<<1,192,0,stream>>>(gq_gamma, gq_beta, gk_gamma, gk_beta, ws);
  samples_kernel<<<240,192,0,stream>>>(v1, gk_w, ws+WS_GK_SCALE, ws+WS_GK_SHIFT, idxs,
                                       ws+WS_SAMPT, ws+WS_SAMP2T);
  head_apply_mfma<<<2048,256,0,stream>>>(v2, gq_w, ws+WS_GQ_SCALE, ws+WS_GQ_SHIFT,
                                         ws+WS_SEGX2, ws+WS_SEGG2);
  anchor2x_kernel<<<512,128,0,stream>>>(ws+WS_SEGX2, ws+WS_ANCHOR1, ws+WS_SEGG2, ws+WS_ANCHOR2);
  sim2_mfma<<<dim3(30,16),256,0,stream>>>(ws+WS_ANCHOR2, ws+WS_SAMP2T, ws+WS_SROW);
  lcon12_kernel<<<512,256,0,stream>>>(ws+WS_ANCHOR1, ws+WS_SAMPT, ws+WS_SROW, bg, out);
}